// Round 20
// baseline (96.996 us; speedup 1.0000x reference)
//
#include <hip/hip_runtime.h>

#define NB 8
#define SD 512
#define HW 128
#define EPS 1e-5f

__device__ __forceinline__ int refl(int r) { return r < 0 ? 1 : (r > 127 ? 126 : r); }

// ============ prep: interleaved 1:1 — even b: full-channel stats | odd b: gen_dw ======
// XCD-swizzled (4096 % 8 == 0): each XCD gets a contiguous 512-block run, so the 8
// gen_dw blocks sharing one dww chunk (n-fastest) land on ONE XCD's L2, and stats
// blocks cover a contiguous pred region per XCD.
__global__ __launch_bounds__(256) void prep_k(const float* __restrict__ pred,
                                              const float* __restrict__ style,
                                              const float* __restrict__ dww,
                                              const float* __restrict__ dwb,
                                              float* __restrict__ dw_ws,
                                              float* __restrict__ mean_ws,
                                              float* __restrict__ inv_ws) {
    __shared__ float ws4[4], wss4[4];
    int braw = blockIdx.x;           // 4096
    int b = (braw & 7) * 512 + (braw >> 3);    // XCD-contiguous remap
    int t = threadIdx.x;
    int q = b >> 1;
    if ((b & 1) == 0) {
        // ---- instance-norm stats: block per (n,c) ----
        const float4* p = (const float4*)(pred + (size_t)q * HW * HW);
        float s = 0.f, ss = 0.f;
#pragma unroll
        for (int k = 0; k < 16; ++k) {
            float4 v = p[k * 256 + t];
            s  += v.x + v.y + v.z + v.w;
            ss += v.x * v.x + v.y * v.y + v.z * v.z + v.w * v.w;
        }
#pragma unroll
        for (int off = 32; off; off >>= 1) {
            s  += __shfl_down(s, off);
            ss += __shfl_down(ss, off);
        }
        if ((t & 63) == 0) { ws4[t >> 6] = s; wss4[t >> 6] = ss; }
        __syncthreads();
        if (t == 0) {
            float S  = ws4[0] + ws4[1] + ws4[2] + ws4[3];
            float SS = wss4[0] + wss4[1] + wss4[2] + wss4[3];
            float m = S * (1.f / (HW * HW));
            float var = SS * (1.f / (HW * HW)) - m * m;
            mean_ws[q] = m;
            inv_ws[q] = rsqrtf(var + EPS);
        }
    } else {
        // ---- dw kernel generation: wave per f, 4 f per block sharing style ----
        int n = q & 7;                   // n fastest -> dww reuse (now same-XCD)
        int f = ((q >> 3) << 2) + (t >> 6);
        int lane = t & 63;
        float acc[9];
#pragma unroll
        for (int k = 0; k < 9; ++k) acc[k] = 0.f;
#pragma unroll 2
        for (int it = 0; it < 8; ++it) {
            int c = lane + (it << 6);
            const float4* sp = (const float4*)(style + ((size_t)n * SD + c) * 16);
            float st[16];
#pragma unroll
            for (int k = 0; k < 4; ++k) {
                float4 v = sp[k];
                st[k * 4 + 0] = v.x; st[k * 4 + 1] = v.y;
                st[k * 4 + 2] = v.z; st[k * 4 + 3] = v.w;
            }
            float4 w = *(const float4*)(dww + ((size_t)f * SD + c) * 4);
#pragma unroll
            for (int p = 0; p < 3; ++p)
#pragma unroll
                for (int qq = 0; qq < 3; ++qq)
                    acc[p * 3 + qq] += st[p * 4 + qq] * w.x + st[p * 4 + qq + 1] * w.y
                                     + st[(p + 1) * 4 + qq] * w.z + st[(p + 1) * 4 + qq + 1] * w.w;
        }
#pragma unroll
        for (int k = 0; k < 9; ++k)
#pragma unroll
            for (int off = 32; off; off >>= 1) acc[k] += __shfl_down(acc[k], off);
        if (lane == 0) {
            float bias = dwb[f];
#pragma unroll
            for (int k = 0; k < 9; ++k)
                dw_ws[((size_t)n * 1024 + f) * 9 + k] = acc[k] + bias;
        }
    }
}

// ============ fold2: style-mean + pw dots + fold, one block per (n,g) =================
__global__ __launch_bounds__(256) void fold2_k(const float* __restrict__ style,
                                               const float* __restrict__ pkw,
                                               const float* __restrict__ pkb,
                                               const float* __restrict__ pbw,
                                               const float* __restrict__ pbb,
                                               const float* __restrict__ mean_ws,
                                               const float* __restrict__ inv_ws,
                                               float* __restrict__ dw_ws,
                                               float* __restrict__ pwb_ws) {
    __shared__ float s_lds[SD];
    __shared__ float dwl[144], pwkl[16], invl[4], msc[4], pwbl[4];
    int b = blockIdx.x;              // n*64+g
    int n = b >> 6, g = b & 63;
    int t = threadIdx.x;
    size_t dbase = (size_t)(n * 64 + g) * 144;

    // ---- phase A: dw -> LDS, stats -> LDS, style mean -> LDS ----
    if (t < 144) dwl[t] = dw_ws[dbase + t];
    else if (t < 148) {
        int ic = t - 144;
        float m = mean_ws[n * 256 + g * 4 + ic];
        float s = inv_ws[n * 256 + g * 4 + ic];
        invl[ic] = s; msc[ic] = m * s;
    }
#pragma unroll
    for (int c0 = 0; c0 < 2; ++c0) {
        int c = t + (c0 << 8);
        const float4* sp = (const float4*)(style + ((size_t)n * SD + c) * 16);
        float4 a0 = sp[0], a1 = sp[1], a2 = sp[2], a3 = sp[3];
        float sum = a0.x + a0.y + a0.z + a0.w + a1.x + a1.y + a1.z + a1.w
                  + a2.x + a2.y + a2.z + a2.w + a3.x + a3.y + a3.z + a3.w;
        s_lds[c] = sum * (1.f / 16.f);
    }
    __syncthreads();

    // ---- phase B: 20 dots ----
    int wv = t >> 6, lane = t & 63;
#pragma unroll
    for (int qd = 0; qd < 5; ++qd) {
        int u = wv * 5 + qd;
        const float2* wrow = (const float2*)((u < 16)
                              ? (pkw + (size_t)(g * 16 + u) * SD)
                              : (pbw + (size_t)(g * 4 + (u - 16)) * SD));
        float a = 0.f;
#pragma unroll
        for (int it = 0; it < 4; ++it) {
            int c2 = lane + (it << 6);
            float2 x = ((const float2*)s_lds)[c2];
            float2 v = wrow[c2];
            a += x.x * v.x + x.y * v.y;
        }
#pragma unroll
        for (int off = 32; off; off >>= 1) a += __shfl_down(a, off);
        if (lane == 0) {
            if (u < 16) pwkl[u] = a + pkb[g * 16 + u];
            else        pwbl[u - 16] = a + pbb[g * 4 + (u - 16)];
        }
    }
    __syncthreads();

    // ---- phase C: fold (transposed [ic][kh][kw][o] layout for main) ----
    if (t < 144) {
        int o = t / 36, rm = t % 36, ic = rm / 9, k = rm % 9;
        int kh = k / 3, kw = k % 3;
        float a = 0.f;
#pragma unroll
        for (int i = 0; i < 4; ++i) a += pwkl[o * 4 + i] * dwl[(i * 4 + ic) * 9 + k];
        dw_ws[dbase + (size_t)(((ic * 3 + kh) * 3 + kw) * 4 + o)] = a * invl[ic];
    } else if (t < 148) {
        int o = t - 144;
        float cb = 0.f;
#pragma unroll
        for (int i = 0; i < 4; ++i) {
            float s2 = 0.f;
#pragma unroll
            for (int ic = 0; ic < 4; ++ic) {
                float sk = 0.f;
#pragma unroll
                for (int k = 0; k < 9; ++k) sk += dwl[(i * 4 + ic) * 9 + k];
                s2 += msc[ic] * sk;
            }
            cb += pwkl[o * 4 + i] * s2;
        }
        pwb_ws[n * 256 + g * 4 + o] = pwbl[o] - cb;
    }
}

// ============ fused main: direct-global stencil, 2 rows/thread, XCD-swizzled grid =====
__global__ __launch_bounds__(256) void adaconv_main_k(const float* __restrict__ pred,
                                                      const float* __restrict__ Wf,
                                                      const float* __restrict__ Bf,
                                                      float* __restrict__ out) {
    int braw = blockIdx.x;           // 4096
    int b = (braw & 7) * 512 + (braw >> 3);    // XCD-contiguous remap
    int strip = b & 7;
    int g = (b >> 3) & 63;
    int n = b >> 9;
    int t = threadIdx.x;
    const size_t gbase = (size_t)(n * 64 + g);
    const size_t cbase = (size_t)(n * 256 + g * 4);
    int row2 = t >> 5;               // 0..7
    int colq = t & 31;               // cols 4*colq .. +3
    int lane = t & 63;
    int r0 = (strip << 4) + (row2 << 1);       // even, 0..126
    int wr0 = refl(r0 - 1), wr3 = refl(r0 + 2);

    const float* Wp = Wf + gbase * 144;   // block-uniform -> s_load broadcast
    const float* Bp = Bf + gbase * 4;

    // ---- 16 independent coalesced loads: 4 window rows x 4 channels ----
    float4 v[4][4];                  // [ic][window row]
#pragma unroll
    for (int ic = 0; ic < 4; ++ic) {
        const float* pc = pred + (cbase + ic) * (HW * HW) + (colq << 2);
        v[ic][0] = *(const float4*)(pc + wr0 * HW);
        v[ic][1] = *(const float4*)(pc + (size_t)r0 * HW);
        v[ic][2] = *(const float4*)(pc + (size_t)(r0 + 1) * HW);
        v[ic][3] = *(const float4*)(pc + wr3 * HW);
    }

    float acc[2][4][4];
#pragma unroll
    for (int o = 0; o < 4; ++o) {
        float bb = Bp[o];
#pragma unroll
        for (int p = 0; p < 4; ++p) { acc[0][o][p] = bb; acc[1][o][p] = bb; }
    }

#pragma unroll
    for (int ic = 0; ic < 4; ++ic) {
#pragma unroll
        for (int wr = 0; wr < 4; ++wr) {
            float4 vv = v[ic][wr];
            float lw = __shfl(vv.w, lane - 1);      // left neighbor's last elem
            float rx = __shfl(vv.x, lane + 1);      // right neighbor's first elem
            float e0 = (colq == 0)  ? vv.y : lw;    // reflect col -1 -> col 1
            float e5 = (colq == 31) ? vv.z : rx;    // reflect col 128 -> col 126
            float e[6] = {e0, vv.x, vv.y, vv.z, vv.w, e5};
#pragma unroll
            for (int ro = 0; ro < 2; ++ro) {
                int kh = wr - ro;
                if (kh < 0 || kh > 2) continue;
                const float* wp = Wp + (ic * 3 + kh) * 12;
#pragma unroll
                for (int kw = 0; kw < 3; ++kw) {
                    float w0 = wp[kw * 4 + 0], w1 = wp[kw * 4 + 1];
                    float w2 = wp[kw * 4 + 2], w3 = wp[kw * 4 + 3];
#pragma unroll
                    for (int p = 0; p < 4; ++p) {
                        acc[ro][0][p] = fmaf(w0, e[p + kw], acc[ro][0][p]);
                        acc[ro][1][p] = fmaf(w1, e[p + kw], acc[ro][1][p]);
                        acc[ro][2][p] = fmaf(w2, e[p + kw], acc[ro][2][p]);
                        acc[ro][3][p] = fmaf(w3, e[p + kw], acc[ro][3][p]);
                    }
                }
            }
        }
    }

#pragma unroll
    for (int ro = 0; ro < 2; ++ro)
#pragma unroll
        for (int o = 0; o < 4; ++o) {
            *(float4*)(out + (cbase + o) * (HW * HW) + (size_t)(r0 + ro) * HW + (colq << 2)) =
                make_float4(acc[ro][o][0], acc[ro][o][1], acc[ro][o][2], acc[ro][o][3]);
        }
}

extern "C" void kernel_launch(void* const* d_in, const int* in_sizes, int n_in,
                              void* d_out, int out_size, void* d_ws, size_t ws_size,
                              hipStream_t stream) {
    const float* style = (const float*)d_in[0];   // [8,512,4,4]
    const float* pred  = (const float*)d_in[1];   // [8,256,128,128]
    const float* dww   = (const float*)d_in[2];   // [1024,512,2,2]
    const float* dwb   = (const float*)d_in[3];   // [1024]
    const float* pkw   = (const float*)d_in[4];   // [1024,512]
    const float* pkb   = (const float*)d_in[5];   // [1024]
    const float* pbw   = (const float*)d_in[6];   // [256,512]
    const float* pbb   = (const float*)d_in[7];   // [256]
    float* out = (float*)d_out;

    float* ws      = (float*)d_ws;
    float* dw_ws   = ws + 4096;     // 73728 (raw dw kernels, folded+transposed in place)
    float* pwb_ws  = ws + 86016;    // 2048 (folded bias)
    float* mean_ws = ws + 88064;    // 2048
    float* inv_ws  = ws + 90112;    // 2048  (end: 92160 floats)

    prep_k<<<4096, 256, 0, stream>>>(pred, style, dww, dwb, dw_ws, mean_ws, inv_ws);
    fold2_k<<<NB * 64, 256, 0, stream>>>(style, pkw, pkb, pbw, pbb,
                                         mean_ws, inv_ws, dw_ws, pwb_ws);
    adaconv_main_k<<<4096, 256, 0, stream>>>(pred, dw_ws, pwb_ws, out);
}

// Round 21
// 92.241 us; speedup vs baseline: 1.0515x; 1.0515x over previous
//
#include <hip/hip_runtime.h>

#define NB 8
#define SD 512
#define HW 128
#define EPS 1e-5f

__device__ __forceinline__ int refl(int r) { return r < 0 ? 1 : (r > 127 ? 126 : r); }

// ============ prep: interleaved 1:1 — even b: full-channel stats | odd b: gen_dw ======
// NOT XCD-swizzled: streaming stats blocks benefit from default round-robin spread
// (R20 measured swizzle here = -4.4 us).
__global__ __launch_bounds__(256) void prep_k(const float* __restrict__ pred,
                                              const float* __restrict__ style,
                                              const float* __restrict__ dww,
                                              const float* __restrict__ dwb,
                                              float* __restrict__ dw_ws,
                                              float* __restrict__ mean_ws,
                                              float* __restrict__ inv_ws) {
    __shared__ float ws4[4], wss4[4];
    int b = blockIdx.x, t = threadIdx.x;
    int q = b >> 1;
    if ((b & 1) == 0) {
        // ---- instance-norm stats: block per (n,c) ----
        const float4* p = (const float4*)(pred + (size_t)q * HW * HW);
        float s = 0.f, ss = 0.f;
#pragma unroll
        for (int k = 0; k < 16; ++k) {
            float4 v = p[k * 256 + t];
            s  += v.x + v.y + v.z + v.w;
            ss += v.x * v.x + v.y * v.y + v.z * v.z + v.w * v.w;
        }
#pragma unroll
        for (int off = 32; off; off >>= 1) {
            s  += __shfl_down(s, off);
            ss += __shfl_down(ss, off);
        }
        if ((t & 63) == 0) { ws4[t >> 6] = s; wss4[t >> 6] = ss; }
        __syncthreads();
        if (t == 0) {
            float S  = ws4[0] + ws4[1] + ws4[2] + ws4[3];
            float SS = wss4[0] + wss4[1] + wss4[2] + wss4[3];
            float m = S * (1.f / (HW * HW));
            float var = SS * (1.f / (HW * HW)) - m * m;
            mean_ws[q] = m;
            inv_ws[q] = rsqrtf(var + EPS);
        }
    } else {
        // ---- dw kernel generation: wave per f, 4 f per block sharing style ----
        int n = q & 7;                   // n fastest -> dww reuse
        int f = ((q >> 3) << 2) + (t >> 6);
        int lane = t & 63;
        float acc[9];
#pragma unroll
        for (int k = 0; k < 9; ++k) acc[k] = 0.f;
#pragma unroll 2
        for (int it = 0; it < 8; ++it) {
            int c = lane + (it << 6);
            const float4* sp = (const float4*)(style + ((size_t)n * SD + c) * 16);
            float st[16];
#pragma unroll
            for (int k = 0; k < 4; ++k) {
                float4 v = sp[k];
                st[k * 4 + 0] = v.x; st[k * 4 + 1] = v.y;
                st[k * 4 + 2] = v.z; st[k * 4 + 3] = v.w;
            }
            float4 w = *(const float4*)(dww + ((size_t)f * SD + c) * 4);
#pragma unroll
            for (int p = 0; p < 3; ++p)
#pragma unroll
                for (int qq = 0; qq < 3; ++qq)
                    acc[p * 3 + qq] += st[p * 4 + qq] * w.x + st[p * 4 + qq + 1] * w.y
                                     + st[(p + 1) * 4 + qq] * w.z + st[(p + 1) * 4 + qq + 1] * w.w;
        }
#pragma unroll
        for (int k = 0; k < 9; ++k)
#pragma unroll
            for (int off = 32; off; off >>= 1) acc[k] += __shfl_down(acc[k], off);
        if (lane == 0) {
            float bias = dwb[f];
#pragma unroll
            for (int k = 0; k < 9; ++k)
                dw_ws[((size_t)n * 1024 + f) * 9 + k] = acc[k] + bias;
        }
    }
}

// ============ fold2: style-mean + pw dots + fold, one block per (n,g) =================
__global__ __launch_bounds__(256) void fold2_k(const float* __restrict__ style,
                                               const float* __restrict__ pkw,
                                               const float* __restrict__ pkb,
                                               const float* __restrict__ pbw,
                                               const float* __restrict__ pbb,
                                               const float* __restrict__ mean_ws,
                                               const float* __restrict__ inv_ws,
                                               float* __restrict__ dw_ws,
                                               float* __restrict__ pwb_ws) {
    __shared__ float s_lds[SD];
    __shared__ float dwl[144], pwkl[16], invl[4], msc[4], pwbl[4];
    int b = blockIdx.x;              // n*64+g
    int n = b >> 6, g = b & 63;
    int t = threadIdx.x;
    size_t dbase = (size_t)(n * 64 + g) * 144;

    // ---- phase A: dw -> LDS, stats -> LDS, style mean -> LDS ----
    if (t < 144) dwl[t] = dw_ws[dbase + t];
    else if (t < 148) {
        int ic = t - 144;
        float m = mean_ws[n * 256 + g * 4 + ic];
        float s = inv_ws[n * 256 + g * 4 + ic];
        invl[ic] = s; msc[ic] = m * s;
    }
#pragma unroll
    for (int c0 = 0; c0 < 2; ++c0) {
        int c = t + (c0 << 8);
        const float4* sp = (const float4*)(style + ((size_t)n * SD + c) * 16);
        float4 a0 = sp[0], a1 = sp[1], a2 = sp[2], a3 = sp[3];
        float sum = a0.x + a0.y + a0.z + a0.w + a1.x + a1.y + a1.z + a1.w
                  + a2.x + a2.y + a2.z + a2.w + a3.x + a3.y + a3.z + a3.w;
        s_lds[c] = sum * (1.f / 16.f);
    }
    __syncthreads();

    // ---- phase B: 20 dots ----
    int wv = t >> 6, lane = t & 63;
#pragma unroll
    for (int qd = 0; qd < 5; ++qd) {
        int u = wv * 5 + qd;
        const float2* wrow = (const float2*)((u < 16)
                              ? (pkw + (size_t)(g * 16 + u) * SD)
                              : (pbw + (size_t)(g * 4 + (u - 16)) * SD));
        float a = 0.f;
#pragma unroll
        for (int it = 0; it < 4; ++it) {
            int c2 = lane + (it << 6);
            float2 x = ((const float2*)s_lds)[c2];
            float2 v = wrow[c2];
            a += x.x * v.x + x.y * v.y;
        }
#pragma unroll
        for (int off = 32; off; off >>= 1) a += __shfl_down(a, off);
        if (lane == 0) {
            if (u < 16) pwkl[u] = a + pkb[g * 16 + u];
            else        pwbl[u - 16] = a + pbb[g * 4 + (u - 16)];
        }
    }
    __syncthreads();

    // ---- phase C: fold (transposed [ic][kh][kw][o] layout for main) ----
    if (t < 144) {
        int o = t / 36, rm = t % 36, ic = rm / 9, k = rm % 9;
        int kh = k / 3, kw = k % 3;
        float a = 0.f;
#pragma unroll
        for (int i = 0; i < 4; ++i) a += pwkl[o * 4 + i] * dwl[(i * 4 + ic) * 9 + k];
        dw_ws[dbase + (size_t)(((ic * 3 + kh) * 3 + kw) * 4 + o)] = a * invl[ic];
    } else if (t < 148) {
        int o = t - 144;
        float cb = 0.f;
#pragma unroll
        for (int i = 0; i < 4; ++i) {
            float s2 = 0.f;
#pragma unroll
            for (int ic = 0; ic < 4; ++ic) {
                float sk = 0.f;
#pragma unroll
                for (int k = 0; k < 9; ++k) sk += dwl[(i * 4 + ic) * 9 + k];
                s2 += msc[ic] * sk;
            }
            cb += pwkl[o * 4 + i] * s2;
        }
        pwb_ws[n * 256 + g * 4 + o] = pwbl[o] - cb;
    }
}

// ============ fused main: direct-global stencil, 2 rows/thread, XCD-swizzled grid =====
// Bijective XCD swizzle (4096 % 8 == 0): all 8 strips of a (n,g) share one XCD's L2
// (halo rows + weight record reuse). Measured +3.0 us vs unswizzled (R19).
__global__ __launch_bounds__(256) void adaconv_main_k(const float* __restrict__ pred,
                                                      const float* __restrict__ Wf,
                                                      const float* __restrict__ Bf,
                                                      float* __restrict__ out) {
    int braw = blockIdx.x;           // 4096
    int b = (braw & 7) * 512 + (braw >> 3);    // XCD-contiguous remap
    int strip = b & 7;
    int g = (b >> 3) & 63;
    int n = b >> 9;
    int t = threadIdx.x;
    const size_t gbase = (size_t)(n * 64 + g);
    const size_t cbase = (size_t)(n * 256 + g * 4);
    int row2 = t >> 5;               // 0..7
    int colq = t & 31;               // cols 4*colq .. +3
    int lane = t & 63;
    int r0 = (strip << 4) + (row2 << 1);       // even, 0..126
    int wr0 = refl(r0 - 1), wr3 = refl(r0 + 2);

    const float* Wp = Wf + gbase * 144;   // block-uniform -> s_load broadcast
    const float* Bp = Bf + gbase * 4;

    // ---- 16 independent coalesced loads: 4 window rows x 4 channels ----
    float4 v[4][4];                  // [ic][window row]
#pragma unroll
    for (int ic = 0; ic < 4; ++ic) {
        const float* pc = pred + (cbase + ic) * (HW * HW) + (colq << 2);
        v[ic][0] = *(const float4*)(pc + wr0 * HW);
        v[ic][1] = *(const float4*)(pc + (size_t)r0 * HW);
        v[ic][2] = *(const float4*)(pc + (size_t)(r0 + 1) * HW);
        v[ic][3] = *(const float4*)(pc + wr3 * HW);
    }

    float acc[2][4][4];
#pragma unroll
    for (int o = 0; o < 4; ++o) {
        float bb = Bp[o];
#pragma unroll
        for (int p = 0; p < 4; ++p) { acc[0][o][p] = bb; acc[1][o][p] = bb; }
    }

#pragma unroll
    for (int ic = 0; ic < 4; ++ic) {
#pragma unroll
        for (int wr = 0; wr < 4; ++wr) {
            float4 vv = v[ic][wr];
            float lw = __shfl(vv.w, lane - 1);      // left neighbor's last elem
            float rx = __shfl(vv.x, lane + 1);      // right neighbor's first elem
            float e0 = (colq == 0)  ? vv.y : lw;    // reflect col -1 -> col 1
            float e5 = (colq == 31) ? vv.z : rx;    // reflect col 128 -> col 126
            float e[6] = {e0, vv.x, vv.y, vv.z, vv.w, e5};
#pragma unroll
            for (int ro = 0; ro < 2; ++ro) {
                int kh = wr - ro;
                if (kh < 0 || kh > 2) continue;
                const float* wp = Wp + (ic * 3 + kh) * 12;
#pragma unroll
                for (int kw = 0; kw < 3; ++kw) {
                    float w0 = wp[kw * 4 + 0], w1 = wp[kw * 4 + 1];
                    float w2 = wp[kw * 4 + 2], w3 = wp[kw * 4 + 3];
#pragma unroll
                    for (int p = 0; p < 4; ++p) {
                        acc[ro][0][p] = fmaf(w0, e[p + kw], acc[ro][0][p]);
                        acc[ro][1][p] = fmaf(w1, e[p + kw], acc[ro][1][p]);
                        acc[ro][2][p] = fmaf(w2, e[p + kw], acc[ro][2][p]);
                        acc[ro][3][p] = fmaf(w3, e[p + kw], acc[ro][3][p]);
                    }
                }
            }
        }
    }

#pragma unroll
    for (int ro = 0; ro < 2; ++ro)
#pragma unroll
        for (int o = 0; o < 4; ++o) {
            *(float4*)(out + (cbase + o) * (HW * HW) + (size_t)(r0 + ro) * HW + (colq << 2)) =
                make_float4(acc[ro][o][0], acc[ro][o][1], acc[ro][o][2], acc[ro][o][3]);
        }
}

extern "C" void kernel_launch(void* const* d_in, const int* in_sizes, int n_in,
                              void* d_out, int out_size, void* d_ws, size_t ws_size,
                              hipStream_t stream) {
    const float* style = (const float*)d_in[0];   // [8,512,4,4]
    const float* pred  = (const float*)d_in[1];   // [8,256,128,128]
    const float* dww   = (const float*)d_in[2];   // [1024,512,2,2]
    const float* dwb   = (const float*)d_in[3];   // [1024]
    const float* pkw   = (const float*)d_in[4];   // [1024,512]
    const float* pkb   = (const float*)d_in[5];   // [1024]
    const float* pbw   = (const float*)d_in[6];   // [256,512]
    const float* pbb   = (const float*)d_in[7];   // [256]
    float* out = (float*)d_out;

    float* ws      = (float*)d_ws;
    float* dw_ws   = ws + 4096;     // 73728 (raw dw kernels, folded+transposed in place)
    float* pwb_ws  = ws + 86016;    // 2048 (folded bias)
    float* mean_ws = ws + 88064;    // 2048
    float* inv_ws  = ws + 90112;    // 2048  (end: 92160 floats)

    prep_k<<<4096, 256, 0, stream>>>(pred, style, dww, dwb, dw_ws, mean_ws, inv_ws);
    fold2_k<<<NB * 64, 256, 0, stream>>>(style, pkw, pkb, pbw, pbb,
                                         mean_ws, inv_ws, dw_ws, pwb_ws);
    adaconv_main_k<<<4096, 256, 0, stream>>>(pred, dw_ws, pwb_ws, out);
}